// Round 3
// baseline (255.279 us; speedup 1.0000x reference)
//
#include <hip/hip_runtime.h>
#include <math.h>

#define BB 2
#define NN 4096
#define DIM 768
#define QSTRIDE 20  // 8 (q head0) + 8 (q head1) + w0 + w1 + 2 pad, float4-aligned

// ---------------------------------------------------------------------------
// proj: fused qproj + kproj (independent work, block-level split).
// Blocks [0,1024): qw = query_tokens @ Wq (8192 x 768 -> 18)
// Blocks [1024,2048): k = key_tokens @ Wk (8192 x 768 -> 8) + 2D sinusoidal PE
// One wave handles 2 rows, lane-parallel over dim, butterfly reduce.
// ---------------------------------------------------------------------------
__global__ __launch_bounds__(256) void proj_kernel(const float* __restrict__ qt,
                                                   const float* __restrict__ kt,
                                                   const float* __restrict__ Wq,
                                                   const float* __restrict__ Wk,
                                                   const int* __restrict__ hp,
                                                   const int* __restrict__ wp,
                                                   float* __restrict__ qd,
                                                   float* __restrict__ kd) {
  const int tid = threadIdx.x;
  const int lane = tid & 63;
  const int r = lane >> 5;
  const int l = lane & 31;

  if (blockIdx.x < 1024) {
    // ---------------- qproj ----------------
    const int pair = blockIdx.x * 4 + (tid >> 6);
    const int row0 = pair * 2;
    const float* xr0 = qt + (size_t)row0 * DIM;
    const float* xr1 = xr0 + DIM;

    float acc0[18], acc1[18];
#pragma unroll
    for (int c = 0; c < 18; ++c) { acc0[c] = 0.f; acc1[c] = 0.f; }

#pragma unroll
    for (int j = 0; j < DIM / 64; ++j) {
      const int i = lane + 64 * j;
      const float x0 = xr0[i];
      const float x1 = xr1[i];
      const float* wr = Wq + i * 18;  // 72 B stride: 8B-aligned float2 loads
#pragma unroll
      for (int c = 0; c < 9; ++c) {
        const float2 w2 = *(const float2*)(wr + 2 * c);
        acc0[2 * c]     = fmaf(x0, w2.x, acc0[2 * c]);
        acc0[2 * c + 1] = fmaf(x0, w2.y, acc0[2 * c + 1]);
        acc1[2 * c]     = fmaf(x1, w2.x, acc1[2 * c]);
        acc1[2 * c + 1] = fmaf(x1, w2.y, acc1[2 * c + 1]);
      }
    }

#pragma unroll
    for (int off = 32; off >= 1; off >>= 1) {
#pragma unroll
      for (int c = 0; c < 18; ++c) {
        acc0[c] += __shfl_xor(acc0[c], off, 64);
        acc1[c] += __shfl_xor(acc1[c], off, 64);
      }
    }

    if (l < 18) {
      // dst slot l -> qw column: l<8 -> l ; 8<=l<16 -> l+1 ; 16 -> 8 ; 17 -> 17
      int src;
      if (l < 8) src = l;
      else if (l < 16) src = l + 1;
      else if (l == 16) src = 8;
      else src = 17;
      float v = r ? acc1[0] : acc0[0];
#pragma unroll
      for (int c = 1; c < 18; ++c) {
        const float cand = r ? acc1[c] : acc0[c];
        v = (src == c) ? cand : v;
      }
      qd[(size_t)(row0 + r) * QSTRIDE + l] = v;
    }
  } else {
    // ---------------- kproj ----------------
    const int pair = (blockIdx.x - 1024) * 4 + (tid >> 6);
    const int row0 = pair * 2;
    const float* xr0 = kt + (size_t)row0 * DIM;
    const float* xr1 = xr0 + DIM;

    float acc0[8], acc1[8];
#pragma unroll
    for (int c = 0; c < 8; ++c) { acc0[c] = 0.f; acc1[c] = 0.f; }

#pragma unroll
    for (int j = 0; j < DIM / 64; ++j) {
      const int i = lane + 64 * j;
      const float x0 = xr0[i];
      const float x1 = xr1[i];
      const float4 wa = *(const float4*)(Wk + i * 8);
      const float4 wb = *(const float4*)(Wk + i * 8 + 4);
      acc0[0] = fmaf(x0, wa.x, acc0[0]); acc0[1] = fmaf(x0, wa.y, acc0[1]);
      acc0[2] = fmaf(x0, wa.z, acc0[2]); acc0[3] = fmaf(x0, wa.w, acc0[3]);
      acc0[4] = fmaf(x0, wb.x, acc0[4]); acc0[5] = fmaf(x0, wb.y, acc0[5]);
      acc0[6] = fmaf(x0, wb.z, acc0[6]); acc0[7] = fmaf(x0, wb.w, acc0[7]);
      acc1[0] = fmaf(x1, wa.x, acc1[0]); acc1[1] = fmaf(x1, wa.y, acc1[1]);
      acc1[2] = fmaf(x1, wa.z, acc1[2]); acc1[3] = fmaf(x1, wa.w, acc1[3]);
      acc1[4] = fmaf(x1, wb.x, acc1[4]); acc1[5] = fmaf(x1, wb.y, acc1[5]);
      acc1[6] = fmaf(x1, wb.z, acc1[6]); acc1[7] = fmaf(x1, wb.w, acc1[7]);
    }

#pragma unroll
    for (int off = 32; off >= 1; off >>= 1) {
#pragma unroll
      for (int c = 0; c < 8; ++c) {
        acc0[c] += __shfl_xor(acc0[c], off, 64);
        acc1[c] += __shfl_xor(acc1[c], off, 64);
      }
    }

    if (l < 8) {
      const int row = row0 + r;
      const int h = hp[0];
      const int w = wp[0];
      const int n = row % NN;
      const int yi = n / w;
      const int xi = n - yi * w;
      const int hd = (h - 1) > 1 ? (h - 1) : 1;
      const int wd = (w - 1) > 1 ? (w - 1) : 1;
      const float yv = (float)yi / (float)hd;
      const float xv = (float)xi / (float)wd;
      const float base = (l < 4) ? yv : xv;
      const float sc = (l < 4) ? (float)h : (float)w;
      const float fr = (l & 2) ? 0.01f : 1.0f;
      const float ang = base * fr * sc;
      const float pe = (l & 1) ? cosf(ang) : sinf(ang);
      float v = r ? acc1[0] : acc0[0];
#pragma unroll
      for (int c = 1; c < 8; ++c) {
        const float cand = r ? acc1[c] : acc0[c];
        v = (l == c) ? cand : v;
      }
      kd[(size_t)row * 8 + l] = v + pe;
    }
  }
}

// ---------------------------------------------------------------------------
// scores: out[b,q,k] = w0*relu(scale*<q0,k>) + w1*relu(scale*<q1,k>) + bias
// LDS-free: qd/kd total 896 KB -> fully L2-resident and shared across blocks.
// Lanes with equal tx (k frags) / equal ty (q frags) share addresses -> the
// coalescer merges them; aggregate L2 read volume ~75 MB (~2 us at 34.5 TB/s).
// Block: 256 threads, tile 32 queries x 64 keys; thread: 2 q x 4 k.
// ---------------------------------------------------------------------------
__device__ __forceinline__ float dot8(const float4 a, const float4 b,
                                      const float4 ka, const float4 kb2) {
  float d = a.x * ka.x;
  d = fmaf(a.y, ka.y, d);
  d = fmaf(a.z, ka.z, d);
  d = fmaf(a.w, ka.w, d);
  d = fmaf(b.x, kb2.x, d);
  d = fmaf(b.y, kb2.y, d);
  d = fmaf(b.z, kb2.z, d);
  d = fmaf(b.w, kb2.w, d);
  return d;
}

__global__ __launch_bounds__(256) void scores_kernel(const float* __restrict__ qd,
                                                     const float* __restrict__ kd,
                                                     const float* __restrict__ bias,
                                                     float* __restrict__ out) {
  const int tid = threadIdx.x;
  const int kb = blockIdx.x;  // 64-key tile
  const int qb = blockIdx.y;  // 32-query tile
  const int b  = blockIdx.z;

  const int tx = tid & 15;
  const int ty = tid >> 4;
  const float sb = bias[0];
  const float scale = 0.35355339059327373f;  // 8^-0.5

  // 4 keys x 8 floats from L2 (8 independent float4 loads)
  const float* kp = kd + ((size_t)b * NN + kb * 64 + tx * 4) * 8;
  float4 ka[4], kb4[4];
#pragma unroll
  for (int i = 0; i < 4; ++i) {
    ka[i]  = *(const float4*)(kp + i * 8);
    kb4[i] = *(const float4*)(kp + i * 8 + 4);
  }

  // 2 query rows x (16 q floats + 2 w floats) from L2
  const float* qp0 = qd + ((size_t)b * NN + qb * 32 + ty * 2) * QSTRIDE;
  const float* qp1 = qp0 + QSTRIDE;
  const float4 q0a = *(const float4*)(qp0);
  const float4 q0b = *(const float4*)(qp0 + 4);
  const float4 q0c = *(const float4*)(qp0 + 8);
  const float4 q0d = *(const float4*)(qp0 + 12);
  const float2 w0v = *(const float2*)(qp0 + 16);
  const float4 q1a = *(const float4*)(qp1);
  const float4 q1b = *(const float4*)(qp1 + 4);
  const float4 q1c = *(const float4*)(qp1 + 8);
  const float4 q1d = *(const float4*)(qp1 + 12);
  const float2 w1v = *(const float2*)(qp1 + 16);

  float4 res0, res1;
  float* r0 = (float*)&res0;
  float* r1 = (float*)&res1;
#pragma unroll
  for (int i = 0; i < 4; ++i) {
    float d00 = dot8(q0a, q0b, ka[i], kb4[i]);  // q row0, head0
    float d01 = dot8(q0c, q0d, ka[i], kb4[i]);  // q row0, head1
    float d10 = dot8(q1a, q1b, ka[i], kb4[i]);  // q row1, head0
    float d11 = dot8(q1c, q1d, ka[i], kb4[i]);  // q row1, head1
    d00 = fmaxf(d00 * scale, 0.f);
    d01 = fmaxf(d01 * scale, 0.f);
    d10 = fmaxf(d10 * scale, 0.f);
    d11 = fmaxf(d11 * scale, 0.f);
    r0[i] = fmaf(w0v.x, d00, fmaf(w0v.y, d01, sb));
    r1[i] = fmaf(w1v.x, d10, fmaf(w1v.y, d11, sb));
  }

  const size_t q0 = (size_t)b * NN + qb * 32 + ty * 2;
  float* op0 = out + q0 * (size_t)NN + (size_t)(kb * 64 + tx * 4);
  float* op1 = op0 + NN;
  *(float4*)op0 = res0;
  *(float4*)op1 = res1;
}

// ---------------------------------------------------------------------------
extern "C" void kernel_launch(void* const* d_in, const int* in_sizes, int n_in,
                              void* d_out, int out_size, void* d_ws, size_t ws_size,
                              hipStream_t stream) {
  const float* qt = (const float*)d_in[0];  // (2, 4096, 768)
  const float* kt = (const float*)d_in[1];  // (2, 4096, 768)
  const float* Wq = (const float*)d_in[2];  // (768, 18)
  const float* Wk = (const float*)d_in[3];  // (768, 8)
  const float* sb = (const float*)d_in[4];  // (1,1,1)
  const int* hp = (const int*)d_in[5];      // height (64)
  const int* wp = (const int*)d_in[6];      // width  (64)

  float* qd = (float*)d_ws;                      // 8192 * 20 floats = 640 KB
  float* kd = qd + (size_t)BB * NN * QSTRIDE;    // 8192 * 8 floats  = 256 KB
  float* outp = (float*)d_out;                   // (2, 4096, 4096) fp32

  // 8192 q-rows + 8192 k-rows, 2 rows/wave, 4 waves/block -> 2048 blocks
  proj_kernel<<<2048, 256, 0, stream>>>(qt, kt, Wq, Wk, hp, wp, qd, kd);
  // 64 key-tiles x 128 query-tiles x 2 batches
  scores_kernel<<<dim3(64, NN / 32, BB), 256, 0, stream>>>(qd, kd, sb, outp);
}

// Round 4
// 204.697 us; speedup vs baseline: 1.2471x; 1.2471x over previous
//
#include <hip/hip_runtime.h>
#include <math.h>

#define BB 2
#define NN 4096
#define DIM 768
#define QSTRIDE 20  // 8 (q head0) + 8 (q head1) + w0' + w1' + 2 pad
#define SCALE 0.35355339059327373f  // 8^-0.5, folded into w at qproj

// ---------------------------------------------------------------------------
// proj: fused qproj + kproj (block-level split, one launch for overlap).
// Blocks [0,512): qw = query_tokens @ Wq. Wq staged in LDS (natural stride-18
//   layout; b64 reads are 4-way bank aliased = 1.58x, acceptable). 4 rows per
//   wave to amortize the weight reads; butterfly reduce 72 accumulators.
//   Output per row (stride 20): [q0(8), q1(8), w0*SCALE, w1*SCALE, pad(2)]
// Blocks [512,1536): k = key_tokens @ Wk + 2D sinusoidal PE (2 rows/wave;
//   Wk float4 loads are only 32 L1 transactions/instr, L1-resident).
// ---------------------------------------------------------------------------
__global__ __launch_bounds__(256) void proj_kernel(const float* __restrict__ qt,
                                                   const float* __restrict__ kt,
                                                   const float* __restrict__ Wq,
                                                   const float* __restrict__ Wk,
                                                   const int* __restrict__ hp,
                                                   const int* __restrict__ wp,
                                                   float* __restrict__ qd,
                                                   float* __restrict__ kd) {
  __shared__ float lw[DIM * 18];  // 55.3 KB (q-blocks only; caps 2 blocks/CU)

  const int tid = threadIdx.x;
  const int lane = tid & 63;
  const int r = lane >> 5;
  const int l = lane & 31;

  if (blockIdx.x < 512) {
    // ---------------- qproj ----------------
    {
      const float4* s4 = (const float4*)Wq;  // 13824 floats = 3456 float4
      float4* d4 = (float4*)lw;
#pragma unroll 1
      for (int t = tid; t < DIM * 18 / 4; t += 256) d4[t] = s4[t];
    }
    __syncthreads();

    const int row0 = (blockIdx.x * 4 + (tid >> 6)) * 4;  // 4 rows per wave
    const float* xr = qt + (size_t)row0 * DIM;

    float acc[4][18];
#pragma unroll
    for (int rr = 0; rr < 4; ++rr)
#pragma unroll
      for (int c = 0; c < 18; ++c) acc[rr][c] = 0.f;

#pragma unroll
    for (int j = 0; j < DIM / 64; ++j) {
      const int i = lane + 64 * j;
      const float x0 = xr[i];
      const float x1 = xr[i + DIM];
      const float x2 = xr[i + 2 * DIM];
      const float x3 = xr[i + 3 * DIM];
      const float* wr = lw + i * 18;
#pragma unroll
      for (int c = 0; c < 9; ++c) {
        const float2 w2 = *(const float2*)(wr + 2 * c);
        acc[0][2*c] = fmaf(x0, w2.x, acc[0][2*c]);
        acc[0][2*c+1] = fmaf(x0, w2.y, acc[0][2*c+1]);
        acc[1][2*c] = fmaf(x1, w2.x, acc[1][2*c]);
        acc[1][2*c+1] = fmaf(x1, w2.y, acc[1][2*c+1]);
        acc[2][2*c] = fmaf(x2, w2.x, acc[2][2*c]);
        acc[2][2*c+1] = fmaf(x2, w2.y, acc[2][2*c+1]);
        acc[3][2*c] = fmaf(x3, w2.x, acc[3][2*c]);
        acc[3][2*c+1] = fmaf(x3, w2.y, acc[3][2*c+1]);
      }
    }

#pragma unroll
    for (int off = 32; off >= 1; off >>= 1)
#pragma unroll
      for (int rr = 0; rr < 4; ++rr)
#pragma unroll
        for (int c = 0; c < 18; ++c)
          acc[rr][c] += __shfl_xor(acc[rr][c], off, 64);

    if (l < 18) {
      // dst slot l -> qw column: l<8 -> l ; 8<=l<16 -> l+1 ; 16 -> 8 ; 17 -> 17
      int src;
      if (l < 8) src = l;
      else if (l < 16) src = l + 1;
      else if (l == 16) src = 8;
      else src = 17;
      float v0 = 0.f, v1 = 0.f;
#pragma unroll
      for (int c = 0; c < 18; ++c) {
        const float a0 = r ? acc[1][c] : acc[0][c];
        const float a1 = r ? acc[3][c] : acc[2][c];
        v0 = (src == c) ? a0 : v0;
        v1 = (src == c) ? a1 : v1;
      }
      if (l >= 16) { v0 *= SCALE; v1 *= SCALE; }
      qd[(size_t)(row0 + r) * QSTRIDE + l] = v0;      // rows row0+0 / row0+1
      qd[(size_t)(row0 + 2 + r) * QSTRIDE + l] = v1;  // rows row0+2 / row0+3
    }
  } else {
    // ---------------- kproj ----------------
    const int pair = (blockIdx.x - 512) * 4 + (tid >> 6);
    const int row0 = pair * 2;
    const float* xr0 = kt + (size_t)row0 * DIM;
    const float* xr1 = xr0 + DIM;

    float acc0[8], acc1[8];
#pragma unroll
    for (int c = 0; c < 8; ++c) { acc0[c] = 0.f; acc1[c] = 0.f; }

#pragma unroll
    for (int j = 0; j < DIM / 64; ++j) {
      const int i = lane + 64 * j;
      const float x0 = xr0[i];
      const float x1 = xr1[i];
      const float4 wa = *(const float4*)(Wk + i * 8);
      const float4 wb = *(const float4*)(Wk + i * 8 + 4);
      acc0[0] = fmaf(x0, wa.x, acc0[0]); acc0[1] = fmaf(x0, wa.y, acc0[1]);
      acc0[2] = fmaf(x0, wa.z, acc0[2]); acc0[3] = fmaf(x0, wa.w, acc0[3]);
      acc0[4] = fmaf(x0, wb.x, acc0[4]); acc0[5] = fmaf(x0, wb.y, acc0[5]);
      acc0[6] = fmaf(x0, wb.z, acc0[6]); acc0[7] = fmaf(x0, wb.w, acc0[7]);
      acc1[0] = fmaf(x1, wa.x, acc1[0]); acc1[1] = fmaf(x1, wa.y, acc1[1]);
      acc1[2] = fmaf(x1, wa.z, acc1[2]); acc1[3] = fmaf(x1, wa.w, acc1[3]);
      acc1[4] = fmaf(x1, wb.x, acc1[4]); acc1[5] = fmaf(x1, wb.y, acc1[5]);
      acc1[6] = fmaf(x1, wb.z, acc1[6]); acc1[7] = fmaf(x1, wb.w, acc1[7]);
    }

#pragma unroll
    for (int off = 32; off >= 1; off >>= 1)
#pragma unroll
      for (int c = 0; c < 8; ++c) {
        acc0[c] += __shfl_xor(acc0[c], off, 64);
        acc1[c] += __shfl_xor(acc1[c], off, 64);
      }

    if (l < 8) {
      const int row = row0 + r;
      const int h = hp[0];
      const int w = wp[0];
      const int n = row % NN;
      const int yi = n / w;
      const int xi = n - yi * w;
      const int hd = (h - 1) > 1 ? (h - 1) : 1;
      const int wd = (w - 1) > 1 ? (w - 1) : 1;
      const float yv = (float)yi / (float)hd;
      const float xv = (float)xi / (float)wd;
      const float base = (l < 4) ? yv : xv;
      const float sc = (l < 4) ? (float)h : (float)w;
      const float fr = (l & 2) ? 0.01f : 1.0f;
      const float ang = base * fr * sc;
      const float pe = (l & 1) ? cosf(ang) : sinf(ang);
      float v = r ? acc1[0] : acc0[0];
#pragma unroll
      for (int c = 1; c < 8; ++c) {
        const float cand = r ? acc1[c] : acc0[c];
        v = (l == c) ? cand : v;
      }
      kd[(size_t)row * 8 + l] = v + pe;
    }
  }
}

// ---------------------------------------------------------------------------
// scores: out[b,q,k] = w0'*relu(<q0,k>) + w1'*relu(<q1,k>) + bias  (w' = w*SCALE)
// Wave = 64 consecutive keys (lane = key) x 8 query rows.
//   k: 2 coalesced float4 loads per lane (held in 8 VGPRs, reused x8 rows).
//   q: wave-uniform pointer (readfirstlane on wave id) -> scalar s_load path,
//      q values consumed as the scalar operand of v_fma (no VMEM transactions).
//   stores: 8 per wave, each 64 lanes x 4 B = fully coalesced 256 B.
// ---------------------------------------------------------------------------
__global__ __launch_bounds__(256) void scores_kernel(const float* __restrict__ qd,
                                                     const float* __restrict__ kd,
                                                     const float* __restrict__ bias,
                                                     float* __restrict__ out) {
  const int lane = threadIdx.x & 63;
  const int wv = __builtin_amdgcn_readfirstlane(threadIdx.x >> 6);
  const int kb = blockIdx.x;  // 64-key tile
  const int qb = blockIdx.y;  // 32-query tile (4 waves x 8 rows)
  const int b  = blockIdx.z;

  const float* kp = kd + ((size_t)b * NN + kb * 64 + lane) * 8;
  const float4 k0 = *(const float4*)kp;
  const float4 k1 = *(const float4*)(kp + 4);
  const float sb = bias[0];

  const int row0 = qb * 32 + wv * 8;
  const float* qp = qd + ((size_t)b * NN + row0) * QSTRIDE;
  float* op = out + ((size_t)b * NN + row0) * (size_t)NN + (size_t)(kb * 64 + lane);

#pragma unroll
  for (int rr = 0; rr < 8; ++rr) {
    const float* q = qp + rr * QSTRIDE;
    float d0 = q[0] * k0.x;
    d0 = fmaf(q[1], k0.y, d0);
    d0 = fmaf(q[2], k0.z, d0);
    d0 = fmaf(q[3], k0.w, d0);
    d0 = fmaf(q[4], k1.x, d0);
    d0 = fmaf(q[5], k1.y, d0);
    d0 = fmaf(q[6], k1.z, d0);
    d0 = fmaf(q[7], k1.w, d0);
    float d1 = q[8] * k0.x;
    d1 = fmaf(q[9],  k0.y, d1);
    d1 = fmaf(q[10], k0.z, d1);
    d1 = fmaf(q[11], k0.w, d1);
    d1 = fmaf(q[12], k1.x, d1);
    d1 = fmaf(q[13], k1.y, d1);
    d1 = fmaf(q[14], k1.z, d1);
    d1 = fmaf(q[15], k1.w, d1);
    d0 = fmaxf(d0, 0.f);
    d1 = fmaxf(d1, 0.f);
    op[(size_t)rr * NN] = fmaf(q[16], d0, fmaf(q[17], d1, sb));
  }
}

// ---------------------------------------------------------------------------
extern "C" void kernel_launch(void* const* d_in, const int* in_sizes, int n_in,
                              void* d_out, int out_size, void* d_ws, size_t ws_size,
                              hipStream_t stream) {
  const float* qt = (const float*)d_in[0];  // (2, 4096, 768)
  const float* kt = (const float*)d_in[1];  // (2, 4096, 768)
  const float* Wq = (const float*)d_in[2];  // (768, 18)
  const float* Wk = (const float*)d_in[3];  // (768, 8)
  const float* sb = (const float*)d_in[4];  // (1,1,1)
  const int* hp = (const int*)d_in[5];      // height (64)
  const int* wp = (const int*)d_in[6];      // width  (64)

  float* qd = (float*)d_ws;                      // 8192 * 20 floats = 640 KB
  float* kd = qd + (size_t)BB * NN * QSTRIDE;    // 8192 * 8 floats  = 256 KB
  float* outp = (float*)d_out;                   // (2, 4096, 4096) fp32

  // q: 512 blocks (16 rows each) + k: 1024 blocks (8 rows each)
  proj_kernel<<<1536, 256, 0, stream>>>(qt, kt, Wq, Wk, hp, wp, qd, kd);
  // 64 key-tiles x 128 query-tiles x 2 batches
  scores_kernel<<<dim3(64, NN / 32, BB), 256, 0, stream>>>(qd, kd, sb, outp);
}